// Round 6
// baseline (140.684 us; speedup 1.0000x reference)
//
#include <hip/hip_runtime.h>
#include <cmath>

#define A_CNT 196416
#define C_CNT 90
#define QUADS (A_CNT / 4)            // 49104 quads (4 anchors = 1440 B each)
#define NWI (QUADS / 4)              // 12276 wave-iters (4 quads per wave-iter)
#define TOPK 100u
#define CAPB 2048
#define NB_RED 1024                  // 4 blocks/CU -> 16 waves/CU resident
#define NWAVES 4096                  // 3 rolling iters/wave (12288 slots >= 12276)
#define NB_GAT 192

// ws layout (bytes):
//   [0, 785664)          keys[A]   (uint32 monotonic score keys; 0 = below threshold)
//   [785664, 789760)     hist1[1024] (coarse: idx 0 = zero-key, 1..565 = top16-0x3D4B)
//   [789760, 789824)     ctrl[16]: 0=binB(top16) 1=G 5=candA_cnt 6=candB_cnt 8=doneR 9=doneG
//   [789824, 790336)     candA[128]  (keys strictly above binB; count = G < 100)
//   [790336, 798528)     candB[2048] (keys with top16 == binB)
#define OFF_HIST1 785664u
#define OFF_CTRL  789760u
#define OFF_CANDA 789824u
#define OFF_CANDB 790336u

#define AGENT_LD(p)    __hip_atomic_load((p), __ATOMIC_RELAXED, __HIP_MEMORY_SCOPE_AGENT)
#define AGENT_ST(p, v) __hip_atomic_store((p), (v), __ATOMIC_RELAXED, __HIP_MEMORY_SCOPE_AGENT)

// ---- R11: 16-lane groups, rolling depth-2, 16 waves/CU ---------------------
// Ladder: depth-1@24w/CU=41us, rolling-2@8w/CU=~28us (R7, best), frontload
// variants regress (R9/R10: burst queue delay lands in the first vmcnt wait).
// The reduce phase (~150cy) hides only ~1/6 of HBM latency (~900cy), so the
// rest needs OTHER waves -> raise TLP with the rolling schedule intact.
// 16-lane groups x 6 float4 halve the per-wave payload (48 VGPR), fitting
// launch_bounds(256,4) = 128-VGPR cap = 16 waves/CU. Loads per instruction:
// 4 x 256B contiguous segments (was 8 x 128B). Schedule = R7's L,L,R,L,R,R.

#define LOADQ(V, wi)                                                        \
    {                                                                       \
        const float4* __restrict__ r4_ = cls4 + (size_t)(wi) * 360 + g * 90;\
        _Pragma("unroll")                                                   \
        for (int i_ = 0; i_ < 6; ++i_) {                                    \
            const int j_ = s + 16 * i_;                                     \
            V[i_] = r4_[(j_ < 90) ? j_ : 89];  /* clamp dup; masked below */ \
        }                                                                   \
    }                                                                       \
    __builtin_amdgcn_sched_barrier(0);

// Quad anchors a0..a3 at float offsets 0/90/180/270 within the 360-float quad;
// straddle chunks: j=22 (88,89|90,91) and j=67 (268,269|270,271).
#define REDUCE_EMIT(V, wi)                                                  \
    {                                                                       \
        float m0 = -INFINITY, m1 = -INFINITY, m2 = -INFINITY, m3 = -INFINITY; \
        _Pragma("unroll")                                                   \
        for (int i_ = 0; i_ < 6; ++i_) {                                    \
            const int j_ = s + 16 * i_;                                     \
            const float4 vv = V[i_];                                        \
            const float a01 = fmaxf(vv.x, vv.y), a23 = fmaxf(vv.z, vv.w);   \
            const float all = fmaxf(a01, a23);                              \
            if (j_ < 22)       m0 = fmaxf(m0, all);                         \
            else if (j_ == 22) { m0 = fmaxf(m0, a01); m1 = fmaxf(m1, a23); }\
            else if (j_ < 45)  m1 = fmaxf(m1, all);                         \
            else if (j_ < 67)  m2 = fmaxf(m2, all);                         \
            else if (j_ == 67) { m2 = fmaxf(m2, a01); m3 = fmaxf(m3, a23); }\
            else if (j_ < 90)  m3 = fmaxf(m3, all);                         \
        }                                                                   \
        _Pragma("unroll")                                                   \
        for (int d_ = 1; d_ < 16; d_ <<= 1) {       /* 16-lane group reduce */ \
            m0 = fmaxf(m0, __shfl_xor(m0, d_));                             \
            m1 = fmaxf(m1, __shfl_xor(m1, d_));                             \
            m2 = fmaxf(m2, __shfl_xor(m2, d_));                             \
            m3 = fmaxf(m3, __shfl_xor(m3, d_));                             \
        }                                                                   \
        if (s == 0) {                                                       \
            float p0 = 1.0f / (1.0f + expf(-m0));   /* sigmoid(max)==max(sigmoid) */ \
            float p1 = 1.0f / (1.0f + expf(-m1));                           \
            float p2 = 1.0f / (1.0f + expf(-m2));                           \
            float p3 = 1.0f / (1.0f + expf(-m3));                           \
            unsigned k0 = (p0 > 0.05f) ? __float_as_uint(p0) : 0u;          \
            unsigned k1 = (p1 > 0.05f) ? __float_as_uint(p1) : 0u;          \
            unsigned k2 = (p2 > 0.05f) ? __float_as_uint(p2) : 0u;          \
            unsigned k3 = (p3 > 0.05f) ? __float_as_uint(p3) : 0u;          \
            *(uint4*)(keys + 4 * ((size_t)(wi) * 4 + g)) = make_uint4(k0, k1, k2, k3); \
            unsigned h0 = k0 ? (min(k0 >> 16, 0x3F80u) - 0x3D4Bu) : 0u;     \
            unsigned h1 = k1 ? (min(k1 >> 16, 0x3F80u) - 0x3D4Bu) : 0u;     \
            unsigned h2 = k2 ? (min(k2 >> 16, 0x3F80u) - 0x3D4Bu) : 0u;     \
            unsigned h3 = k3 ? (min(k3 >> 16, 0x3F80u) - 0x3D4Bu) : 0u;     \
            atomicAdd(&lhist[h0], 1u);                                      \
            atomicAdd(&lhist[h1], 1u);                                      \
            atomicAdd(&lhist[h2], 1u);                                      \
            atomicAdd(&lhist[h3], 1u);                                      \
        }                                                                   \
    }

__global__ __launch_bounds__(256, 4) void k_reduce(const float* __restrict__ cls,
                                                   unsigned* __restrict__ keys,
                                                   unsigned* __restrict__ hist1,
                                                   unsigned* __restrict__ ctrl) {
    __shared__ unsigned lhist[576];
    __shared__ unsigned sdata[256];
    __shared__ unsigned sbin[2];
    __shared__ int sflag;
    const int t = threadIdx.x;
    for (int j = t; j < 576; j += 256) lhist[j] = 0u;
    __syncthreads();

    const int lane = t & 63;
    const int g = lane >> 4, s = lane & 15;      // 4 groups of 16 lanes
    const int w = blockIdx.x * 4 + (t >> 6);     // wave id in [0, 4096)
    const float4* __restrict__ cls4 = (const float4*)cls;

    // wave w owns wave-iters {w, w+4096, w+8192} ∩ [0, 12276).
    const int wi0 = w;
    const int wi1 = w + NWAVES;                  // < 8192 < 12276, always valid
    const int wi2 = w + 2 * NWAVES;
    const bool has2 = (wi2 < NWI);               // false for 12 waves
    const int wi2c = has2 ? wi2 : wi0;           // clamped load target; emit guarded

    float4 vA[6], vB[6];
    LOADQ(vA, wi0);                              // 6 loads in flight
    LOADQ(vB, wi1);                              // 12
    REDUCE_EMIT(vA, wi0);                        // waits A; B stays in flight
    LOADQ(vA, wi2c);                             // refill while B lands
    REDUCE_EMIT(vB, wi1);
    if (has2) REDUCE_EMIT(vA, wi2);

    __syncthreads();
    for (int j = t; j < 576; j += 256) {
        unsigned c = lhist[j];
        if (c) atomicAdd(&hist1[j], c);
    }
    __syncthreads();                             // drains each thread's atomics (vmcnt)
    if (t == 0) sflag = (atomicAdd(&ctrl[8], 1u) == NB_RED - 1u) ? 1 : 0;
    __syncthreads();
    if (!sflag) return;

    // ---- fused k_scan (last block only; uniform branch, barriers legal) ----
    const unsigned target = TOPK;
    unsigned ssum = 0;
#pragma unroll
    for (int j = 0; j < 4; ++j) ssum += AGENT_LD(&hist1[t * 4 + j]);
    sdata[t] = ssum;
    for (int d = 1; d < 256; d <<= 1) {          // Hillis-Steele inclusive suffix scan
        __syncthreads();
        unsigned add = (t + d < 256) ? sdata[t + d] : 0u;
        __syncthreads();
        sdata[t] += add;
    }
    __syncthreads();
    {
        unsigned mysuf  = sdata[t];
        unsigned nxtsuf = (t < 255) ? sdata[t + 1] : 0u;
        if (nxtsuf < target && mysuf >= target) { sbin[0] = (unsigned)t; sbin[1] = nxtsuf; }
    }
    __syncthreads();
    const unsigned chunkB = sbin[0];
    const unsigned gAbove = sbin[1];
    sdata[t] = (t < 4) ? AGENT_LD(&hist1[chunkB * 4 + t]) : 0u;
    for (int d = 1; d < 256; d <<= 1) {
        __syncthreads();
        unsigned add = (t + d < 256) ? sdata[t + d] : 0u;
        __syncthreads();
        sdata[t] += add;
    }
    __syncthreads();
    {
        unsigned mysuf  = sdata[t] + gAbove;
        unsigned nxtsuf = ((t < 255) ? sdata[t + 1] : 0u) + gAbove;
        if (nxtsuf < target && mysuf >= target) {
            unsigned bin = chunkB * 4 + (unsigned)t;  // hist index: 0=zeros, 1..565
            ctrl[0] = bin ? (bin + 0x3D4Bu) : 0u;     // true top-16 bits
            ctrl[1] = nxtsuf;                         // G < 100
        }
    }
}

// Kernel 2: gather candidates (one uint4 pass over keys), then the LAST block
// runs the full ranking + argmax + box decode (fused k_final).
__global__ __launch_bounds__(256) void k_gather(const float* __restrict__ cls,
                                                const float* __restrict__ reg,
                                                const float* __restrict__ anc,
                                                const unsigned* __restrict__ keys,
                                                unsigned* __restrict__ ctrl,
                                                unsigned* __restrict__ candA,
                                                unsigned* __restrict__ candB,
                                                float* __restrict__ out) {
    __shared__ unsigned sAi[128], sAk[128];
    __shared__ unsigned sBi[CAPB], sBk[CAPB];
    __shared__ unsigned sel[TOPK];
    __shared__ int sflag;
    const int t = threadIdx.x;

    const unsigned binB = ctrl[0];               // prev kernel -> plain load ok
    const int i4 = blockIdx.x * 256 + t;
    if (i4 < A_CNT / 4) {
        uint4 k = ((const uint4*)keys)[i4];
        const unsigned base = (unsigned)(4 * i4);
#pragma unroll
        for (int j = 0; j < 4; ++j) {
            unsigned kk = (j == 0) ? k.x : (j == 1) ? k.y : (j == 2) ? k.z : k.w;
            unsigned t16 = kk >> 16;
            if (t16 > binB) {
                unsigned q = atomicAdd(&ctrl[5], 1u);
                if (q < 128u) AGENT_ST(&candA[q], base + j);
            } else if (t16 == binB) {
                unsigned q = atomicAdd(&ctrl[6], 1u);
                if (q < (unsigned)CAPB) AGENT_ST(&candB[q], base + j);
            }
        }
    }
    __syncthreads();                             // drains this thread's stores/atomics
    if (t == 0) sflag = (atomicAdd(&ctrl[9], 1u) == (unsigned)NB_GAT - 1u) ? 1 : 0;
    __syncthreads();
    if (!sflag) return;

    // ---- fused k_final (last block only) ----
    const unsigned nA = min(AGENT_LD(&ctrl[5]), 128u);   // exact G < 100
    const unsigned nB = min(AGENT_LD(&ctrl[6]), (unsigned)CAPB);
    const unsigned need = TOPK - nA;                     // >= 1; in-bin count >= need

    if (t < (int)nA) { unsigned i = AGENT_LD(&candA[t]); sAi[t] = i; sAk[t] = keys[i]; }
    for (unsigned e = (unsigned)t; e < nB; e += 256u) {
        unsigned i = AGENT_LD(&candB[e]); sBi[e] = i; sBk[e] = keys[i];
    }
    __syncthreads();

    if (t < (int)nA) {                           // rank strictly-above candidates
        unsigned mi = sAi[t], mk = sAk[t], r = 0;
        for (unsigned j = 0; j < nA; ++j) {
            unsigned ok = sAk[j];
            if (ok > mk || (ok == mk && sAi[j] < mi)) r++;
        }
        sel[r] = mi;
    }
    for (unsigned e = (unsigned)t; e < nB; e += 256u) {  // in-bin: (key desc, idx asc)
        unsigned mi = sBi[e], mk = sBk[e], r = 0;
        for (unsigned j = 0; j < nB; ++j) {
            unsigned ok = sBk[j];
            if (ok > mk || (ok == mk && sBi[j] < mi)) r++;
        }
        if (r < need) sel[nA + r] = mi;
    }
    __syncthreads();

    if (t < (int)TOPK) {
        const unsigned a = sel[t];
        const float2* __restrict__ row = (const float2*)(cls + (size_t)a * C_CNT);
        float2 vr[45];
#pragma unroll
        for (int c = 0; c < 45; ++c) vr[c] = row[c]; // issue all 45 loads up front
        float bv = -INFINITY; int bi = 0;
#pragma unroll
        for (int c = 0; c < 45; ++c) {               // argmax over RAW logits (sigmoid
            if (vr[c].x > bv) { bv = vr[c].x; bi = 2 * c; }      // monotonic; strict > =
            if (vr[c].y > bv) { bv = vr[c].y; bi = 2 * c + 1; }  // first-index semantics)
        }
        float score = __uint_as_float(keys[a]);      // prob bits, or 0.0 if thresholded
        const float4 an = ((const float4*)anc)[a];
        const float4 rg = ((const float4*)reg)[a];
        float wa = an.z - an.x, ha = an.w - an.y;
        float cxa = an.x + 0.5f * wa, cya = an.y + 0.5f * ha;
        float dx = rg.x * 0.1f, dy = rg.y * 0.1f;
        float dw = rg.z * 0.2f, dh = rg.w * 0.2f;
        float cx = cxa + dx * wa, cy = cya + dy * ha;
        float w2 = expf(dw) * wa, h2 = expf(dh) * ha;
        out[t * 4 + 0] = fmaxf(cx - 0.5f * w2, 0.0f);
        out[t * 4 + 1] = fmaxf(cy - 0.5f * h2, 0.0f);
        out[t * 4 + 2] = fminf(cx + 0.5f * w2, 1024.0f);
        out[t * 4 + 3] = fminf(cy + 0.5f * h2, 1024.0f);
        out[400 + t] = score;
        out[500 + t] = (float)bi;
    }
}

extern "C" void kernel_launch(void* const* d_in, const int* in_sizes, int n_in,
                              void* d_out, int out_size, void* d_ws, size_t ws_size,
                              hipStream_t stream) {
    const float* reg = (const float*)d_in[1];
    const float* cls = (const float*)d_in[2];
    const float* anc = (const float*)d_in[3];
    float* out = (float*)d_out;
    char* ws = (char*)d_ws;
    unsigned* keys  = (unsigned*)ws;
    unsigned* hist1 = (unsigned*)(ws + OFF_HIST1);
    unsigned* ctrl  = (unsigned*)(ws + OFF_CTRL);
    unsigned* candA = (unsigned*)(ws + OFF_CANDA);
    unsigned* candB = (unsigned*)(ws + OFF_CANDB);

    // hist1 (4 KB) + ctrl (64 B, incl. done counters) are contiguous.
    hipMemsetAsync(hist1, 0, 4096 + 64, stream);
    k_reduce<<<NB_RED, 256, 0, stream>>>(cls, keys, hist1, ctrl);
    k_gather<<<NB_GAT, 256, 0, stream>>>(cls, reg, anc, keys, ctrl, candA, candB, out);
}

// Round 7
// 137.518 us; speedup vs baseline: 1.0230x; 1.0230x over previous
//
#include <hip/hip_runtime.h>
#include <cmath>

#define A_CNT 196416
#define C_CNT 90
#define QUADS (A_CNT / 4)            // 49104 quads (4 anchors = 1440 B each)
#define NWI (QUADS / 4)              // 12276 wave-iters (4 quads per wave-iter)
#define TOPK 100u
#define CAPB 2048
#define NB_RED 768                   // 3 blocks/CU -> 12 waves/CU resident
#define NWAVES 3072                  // 4 rolling slots/wave (12288 >= 12276)
#define NB_GAT 192

// ws layout (bytes):
//   [0, 785664)          keys[A]   (uint32 monotonic score keys; 0 = below threshold)
//   [785664, 789760)     hist1[1024] (coarse: idx 0 = zero-key, 1..565 = top16-0x3D4B)
//   [789760, 789824)     ctrl[16]: 0=binB(top16) 1=G 5=candA_cnt 6=candB_cnt 8=doneR 9=doneG
//   [789824, 790336)     candA[128]  (keys strictly above binB; count = G < 100)
//   [790336, 798528)     candB[2048] (keys with top16 == binB)
#define OFF_HIST1 785664u
#define OFF_CTRL  789760u
#define OFF_CANDA 789824u
#define OFF_CANDB 790336u

#define AGENT_LD(p)    __hip_atomic_load((p), __ATOMIC_RELAXED, __HIP_MEMORY_SCOPE_AGENT)
#define AGENT_ST(p, v) __hip_atomic_store((p), (v), __ATOMIC_RELAXED, __HIP_MEMORY_SCOPE_AGENT)

// ---- R12: inline-asm load pipeline --------------------------------------
// R5/R6/R11 all collapsed to VGPR_Count 16/16/36: hipcc's pressure heuristic
// re-fuses source-level register buffers with their consumers, leaving <1
// load in flight per wave (1.65 TB/s vs the 6.3 TB/s the m13 copy ubench
// proves). Escalation: global_load_dwordx4 via inline asm with "=&v" outputs
// (unsplittable, forced-live) + manual counted s_waitcnt vmcnt(N) (never 0
// mid-loop) + sched_barrier(0) after each wait (rule 18: VALU consumers can
// hoist past an inline-asm waitcnt otherwise).
// Geometry: 16-lane group owns one quad (90 float4); 5 uniform-offset loads
// (j = s+16i, i<5) + 1 clamped load (j = min(s+80, 89); duplicate of j=89 for
// s>=10 is idempotent under max). Rolling depth-2 over 4 slots. The only VMEM
// in each REDUCE is the single uint4 keys store (+1 on vmcnt): waits are
// vmcnt(6) [A ready], 7 [B ready: storeA+C in flight], 7 [C ready:
// storeB+D in flight], 1 [D ready]. launch_bounds(256,3): 170-VGPR cap,
// ~90 used -> no scratch spill (spill VMEM would corrupt the vmcnt counts).

#define LOADQ(V, wi)                                                        \
    {                                                                       \
        const float4* b_ = cls4 + (size_t)(wi) * 360 + g * 90 + s;          \
        const float4* c_ = cls4 + (size_t)(wi) * 360 + g * 90 +             \
                           ((s + 80 < 90) ? s + 80 : 89);                   \
        asm volatile("global_load_dwordx4 %0, %6, off\n\t"                  \
                     "global_load_dwordx4 %1, %6, off offset:256\n\t"       \
                     "global_load_dwordx4 %2, %6, off offset:512\n\t"       \
                     "global_load_dwordx4 %3, %6, off offset:768\n\t"       \
                     "global_load_dwordx4 %4, %6, off offset:1024\n\t"      \
                     "global_load_dwordx4 %5, %7, off"                      \
                     : "=&v"(V[0]), "=&v"(V[1]), "=&v"(V[2]),               \
                       "=&v"(V[3]), "=&v"(V[4]), "=&v"(V[5])                \
                     : "v"(b_), "v"(c_)                                     \
                     : "memory");                                           \
    }

#define WAITV(N)                                                            \
    asm volatile("s_waitcnt vmcnt(" #N ")" ::: "memory");                   \
    __builtin_amdgcn_sched_barrier(0);

// Quad anchors a0..a3 at float offsets 0/90/180/270 (float4 j: a0=0..22.5,
// a1=22.5..45, a2=45..67.5, a3=67.5..90); straddles at j=22 and j=67.
// V[5] is j in [80,89] -> entirely anchor 3.
#define REDUCE_EMIT(V, wi)                                                  \
    {                                                                       \
        float m0 = -INFINITY, m1 = -INFINITY, m2 = -INFINITY, m3 = -INFINITY; \
        _Pragma("unroll")                                                   \
        for (int i_ = 0; i_ < 5; ++i_) {                                    \
            const int j_ = s + 16 * i_;                                     \
            const float4 vv = V[i_];                                        \
            const float a01 = fmaxf(vv.x, vv.y), a23 = fmaxf(vv.z, vv.w);   \
            const float all = fmaxf(a01, a23);                              \
            if (j_ < 22)       m0 = fmaxf(m0, all);                         \
            else if (j_ == 22) { m0 = fmaxf(m0, a01); m1 = fmaxf(m1, a23); }\
            else if (j_ < 45)  m1 = fmaxf(m1, all);                         \
            else if (j_ < 67)  m2 = fmaxf(m2, all);                         \
            else if (j_ == 67) { m2 = fmaxf(m2, a01); m3 = fmaxf(m3, a23); }\
            else               m3 = fmaxf(m3, all);                         \
        }                                                                   \
        {                                                                   \
            const float4 vv = V[5];                                         \
            m3 = fmaxf(m3, fmaxf(fmaxf(vv.x, vv.y), fmaxf(vv.z, vv.w)));    \
        }                                                                   \
        _Pragma("unroll")                                                   \
        for (int d_ = 1; d_ < 16; d_ <<= 1) {       /* 16-lane group reduce */ \
            m0 = fmaxf(m0, __shfl_xor(m0, d_));                             \
            m1 = fmaxf(m1, __shfl_xor(m1, d_));                             \
            m2 = fmaxf(m2, __shfl_xor(m2, d_));                             \
            m3 = fmaxf(m3, __shfl_xor(m3, d_));                             \
        }                                                                   \
        if (s == 0) {                                                       \
            float p0 = 1.0f / (1.0f + expf(-m0));   /* sigmoid(max)==max(sigmoid) */ \
            float p1 = 1.0f / (1.0f + expf(-m1));                           \
            float p2 = 1.0f / (1.0f + expf(-m2));                           \
            float p3 = 1.0f / (1.0f + expf(-m3));                           \
            unsigned k0 = (p0 > 0.05f) ? __float_as_uint(p0) : 0u;          \
            unsigned k1 = (p1 > 0.05f) ? __float_as_uint(p1) : 0u;          \
            unsigned k2 = (p2 > 0.05f) ? __float_as_uint(p2) : 0u;          \
            unsigned k3 = (p3 > 0.05f) ? __float_as_uint(p3) : 0u;          \
            *(uint4*)(keys + 4 * ((size_t)(wi) * 4 + g)) = make_uint4(k0, k1, k2, k3); \
            unsigned h0 = k0 ? (min(k0 >> 16, 0x3F80u) - 0x3D4Bu) : 0u;     \
            unsigned h1 = k1 ? (min(k1 >> 16, 0x3F80u) - 0x3D4Bu) : 0u;     \
            unsigned h2 = k2 ? (min(k2 >> 16, 0x3F80u) - 0x3D4Bu) : 0u;     \
            unsigned h3 = k3 ? (min(k3 >> 16, 0x3F80u) - 0x3D4Bu) : 0u;     \
            atomicAdd(&lhist[h0], 1u);                                      \
            atomicAdd(&lhist[h1], 1u);                                      \
            atomicAdd(&lhist[h2], 1u);                                      \
            atomicAdd(&lhist[h3], 1u);                                      \
        }                                                                   \
    }

__global__ __launch_bounds__(256, 3) void k_reduce(const float* __restrict__ cls,
                                                   unsigned* __restrict__ keys,
                                                   unsigned* __restrict__ hist1,
                                                   unsigned* __restrict__ ctrl) {
    __shared__ unsigned lhist[576];
    __shared__ unsigned sdata[256];
    __shared__ unsigned sbin[2];
    __shared__ int sflag;
    const int t = threadIdx.x;
    for (int j = t; j < 576; j += 256) lhist[j] = 0u;
    __syncthreads();

    const int lane = t & 63;
    const int g = lane >> 4, s = lane & 15;      // 4 groups of 16 lanes
    const int w = blockIdx.x * 4 + (t >> 6);     // wave id in [0, 3072)
    const float4* __restrict__ cls4 = (const float4*)cls;

    // wave w owns wave-iters {w, w+3072, w+6144, w+9216} ∩ [0, 12276).
    const int wi0 = w;
    const int wi1 = w + NWAVES;
    const int wi2 = w + 2 * NWAVES;              // < 9216+... always < 12276
    const int wi3 = w + 3 * NWAVES;
    const bool has3 = (wi3 < NWI);               // false for 12 waves
    const int wi3c = has3 ? wi3 : wi0;           // clamped load target; emit guarded

    float4 vA[6], vB[6];
    LOADQ(vA, wi0);                              // 6 loads in flight
    LOADQ(vB, wi1);                              // 12
    WAITV(6)                                     // A ready; B stays in flight
    REDUCE_EMIT(vA, wi0);                        // +storeA
    LOADQ(vA, wi2);                              // refill A regs (18-ish in flight)
    WAITV(7)                                     // B ready (storeA + C outstanding)
    REDUCE_EMIT(vB, wi1);                        // +storeB
    LOADQ(vB, wi3c);                             // refill B regs
    WAITV(7)                                     // C ready (storeB + D outstanding)
    REDUCE_EMIT(vA, wi2);                        // +storeC
    WAITV(1)                                     // D ready (storeC may linger)
    if (has3) REDUCE_EMIT(vB, wi3);

    __syncthreads();
    for (int j = t; j < 576; j += 256) {
        unsigned c = lhist[j];
        if (c) atomicAdd(&hist1[j], c);
    }
    __syncthreads();                             // drains each thread's atomics (vmcnt)
    if (t == 0) sflag = (atomicAdd(&ctrl[8], 1u) == NB_RED - 1u) ? 1 : 0;
    __syncthreads();
    if (!sflag) return;

    // ---- fused k_scan (last block only; uniform branch, barriers legal) ----
    const unsigned target = TOPK;
    unsigned ssum = 0;
#pragma unroll
    for (int j = 0; j < 4; ++j) ssum += AGENT_LD(&hist1[t * 4 + j]);
    sdata[t] = ssum;
    for (int d = 1; d < 256; d <<= 1) {          // Hillis-Steele inclusive suffix scan
        __syncthreads();
        unsigned add = (t + d < 256) ? sdata[t + d] : 0u;
        __syncthreads();
        sdata[t] += add;
    }
    __syncthreads();
    {
        unsigned mysuf  = sdata[t];
        unsigned nxtsuf = (t < 255) ? sdata[t + 1] : 0u;
        if (nxtsuf < target && mysuf >= target) { sbin[0] = (unsigned)t; sbin[1] = nxtsuf; }
    }
    __syncthreads();
    const unsigned chunkB = sbin[0];
    const unsigned gAbove = sbin[1];
    sdata[t] = (t < 4) ? AGENT_LD(&hist1[chunkB * 4 + t]) : 0u;
    for (int d = 1; d < 256; d <<= 1) {
        __syncthreads();
        unsigned add = (t + d < 256) ? sdata[t + d] : 0u;
        __syncthreads();
        sdata[t] += add;
    }
    __syncthreads();
    {
        unsigned mysuf  = sdata[t] + gAbove;
        unsigned nxtsuf = ((t < 255) ? sdata[t + 1] : 0u) + gAbove;
        if (nxtsuf < target && mysuf >= target) {
            unsigned bin = chunkB * 4 + (unsigned)t;  // hist index: 0=zeros, 1..565
            ctrl[0] = bin ? (bin + 0x3D4Bu) : 0u;     // true top-16 bits
            ctrl[1] = nxtsuf;                         // G < 100
        }
    }
}

// Kernel 2: gather candidates (one uint4 pass over keys), then the LAST block
// runs the full ranking + argmax + box decode (fused k_final).
__global__ __launch_bounds__(256) void k_gather(const float* __restrict__ cls,
                                                const float* __restrict__ reg,
                                                const float* __restrict__ anc,
                                                const unsigned* __restrict__ keys,
                                                unsigned* __restrict__ ctrl,
                                                unsigned* __restrict__ candA,
                                                unsigned* __restrict__ candB,
                                                float* __restrict__ out) {
    __shared__ unsigned sAi[128], sAk[128];
    __shared__ unsigned sBi[CAPB], sBk[CAPB];
    __shared__ unsigned sel[TOPK];
    __shared__ int sflag;
    const int t = threadIdx.x;

    const unsigned binB = ctrl[0];               // prev kernel -> plain load ok
    const int i4 = blockIdx.x * 256 + t;
    if (i4 < A_CNT / 4) {
        uint4 k = ((const uint4*)keys)[i4];
        const unsigned base = (unsigned)(4 * i4);
#pragma unroll
        for (int j = 0; j < 4; ++j) {
            unsigned kk = (j == 0) ? k.x : (j == 1) ? k.y : (j == 2) ? k.z : k.w;
            unsigned t16 = kk >> 16;
            if (t16 > binB) {
                unsigned q = atomicAdd(&ctrl[5], 1u);
                if (q < 128u) AGENT_ST(&candA[q], base + j);
            } else if (t16 == binB) {
                unsigned q = atomicAdd(&ctrl[6], 1u);
                if (q < (unsigned)CAPB) AGENT_ST(&candB[q], base + j);
            }
        }
    }
    __syncthreads();                             // drains this thread's stores/atomics
    if (t == 0) sflag = (atomicAdd(&ctrl[9], 1u) == (unsigned)NB_GAT - 1u) ? 1 : 0;
    __syncthreads();
    if (!sflag) return;

    // ---- fused k_final (last block only) ----
    const unsigned nA = min(AGENT_LD(&ctrl[5]), 128u);   // exact G < 100
    const unsigned nB = min(AGENT_LD(&ctrl[6]), (unsigned)CAPB);
    const unsigned need = TOPK - nA;                     // >= 1; in-bin count >= need

    if (t < (int)nA) { unsigned i = AGENT_LD(&candA[t]); sAi[t] = i; sAk[t] = keys[i]; }
    for (unsigned e = (unsigned)t; e < nB; e += 256u) {
        unsigned i = AGENT_LD(&candB[e]); sBi[e] = i; sBk[e] = keys[i];
    }
    __syncthreads();

    if (t < (int)nA) {                           // rank strictly-above candidates
        unsigned mi = sAi[t], mk = sAk[t], r = 0;
        for (unsigned j = 0; j < nA; ++j) {
            unsigned ok = sAk[j];
            if (ok > mk || (ok == mk && sAi[j] < mi)) r++;
        }
        sel[r] = mi;
    }
    for (unsigned e = (unsigned)t; e < nB; e += 256u) {  // in-bin: (key desc, idx asc)
        unsigned mi = sBi[e], mk = sBk[e], r = 0;
        for (unsigned j = 0; j < nB; ++j) {
            unsigned ok = sBk[j];
            if (ok > mk || (ok == mk && sBi[j] < mi)) r++;
        }
        if (r < need) sel[nA + r] = mi;
    }
    __syncthreads();

    if (t < (int)TOPK) {
        const unsigned a = sel[t];
        const float2* __restrict__ row = (const float2*)(cls + (size_t)a * C_CNT);
        float2 vr[45];
#pragma unroll
        for (int c = 0; c < 45; ++c) vr[c] = row[c]; // issue all 45 loads up front
        float bv = -INFINITY; int bi = 0;
#pragma unroll
        for (int c = 0; c < 45; ++c) {               // argmax over RAW logits (sigmoid
            if (vr[c].x > bv) { bv = vr[c].x; bi = 2 * c; }      // monotonic; strict > =
            if (vr[c].y > bv) { bv = vr[c].y; bi = 2 * c + 1; }  // first-index semantics)
        }
        float score = __uint_as_float(keys[a]);      // prob bits, or 0.0 if thresholded
        const float4 an = ((const float4*)anc)[a];
        const float4 rg = ((const float4*)reg)[a];
        float wa = an.z - an.x, ha = an.w - an.y;
        float cxa = an.x + 0.5f * wa, cya = an.y + 0.5f * ha;
        float dx = rg.x * 0.1f, dy = rg.y * 0.1f;
        float dw = rg.z * 0.2f, dh = rg.w * 0.2f;
        float cx = cxa + dx * wa, cy = cya + dy * ha;
        float w2 = expf(dw) * wa, h2 = expf(dh) * ha;
        out[t * 4 + 0] = fmaxf(cx - 0.5f * w2, 0.0f);
        out[t * 4 + 1] = fmaxf(cy - 0.5f * h2, 0.0f);
        out[t * 4 + 2] = fminf(cx + 0.5f * w2, 1024.0f);
        out[t * 4 + 3] = fminf(cy + 0.5f * h2, 1024.0f);
        out[400 + t] = score;
        out[500 + t] = (float)bi;
    }
}

extern "C" void kernel_launch(void* const* d_in, const int* in_sizes, int n_in,
                              void* d_out, int out_size, void* d_ws, size_t ws_size,
                              hipStream_t stream) {
    const float* reg = (const float*)d_in[1];
    const float* cls = (const float*)d_in[2];
    const float* anc = (const float*)d_in[3];
    float* out = (float*)d_out;
    char* ws = (char*)d_ws;
    unsigned* keys  = (unsigned*)ws;
    unsigned* hist1 = (unsigned*)(ws + OFF_HIST1);
    unsigned* ctrl  = (unsigned*)(ws + OFF_CTRL);
    unsigned* candA = (unsigned*)(ws + OFF_CANDA);
    unsigned* candB = (unsigned*)(ws + OFF_CANDB);

    // hist1 (4 KB) + ctrl (64 B, incl. done counters) are contiguous.
    hipMemsetAsync(hist1, 0, 4096 + 64, stream);
    k_reduce<<<NB_RED, 256, 0, stream>>>(cls, keys, hist1, ctrl);
    k_gather<<<NB_GAT, 256, 0, stream>>>(cls, reg, anc, keys, ctrl, candA, candB, out);
}